// Round 1
// 523.349 us; speedup vs baseline: 1.0902x; 1.0902x over previous
//
#include <hip/hip_runtime.h>
#include <math.h>

// out[i,j,:] = sinusoidal_emb(atan2(|n_i x n_j|, n_i.n_j) * 180/(15pi)) @ W.T + b
// N=1024^2 pairs, HIDDEN=128, fp32 out (512 MiB -> HBM-write-bound, ~90us floor).
// Output row is a smooth 1-D function of angle -> 127-row table of (emb@W.T+b),
// lerp per pair (err ~7e-4 << 4.8e-2 threshold).
//
// R(this): FUSED streaming kernel. Previous 3-kernel version was latency-bound:
// lerp_out's per-iteration dependent tv[] global load forced s_waitcnt vmcnt(0)
// (draining the store queue) + cross-XCD L2 miss latency every iteration at only
// 2 waves/SIMD. Now each lane computes its pair's angle in-register (identical
// math -> identical absmax), then a 32-step loop broadcasts t via one
// ds_bpermute and lerps from LDS. Inner loop has ZERO global loads -> stores
// stream at full BW. Also deletes the 4MB tv write + 4MB scattered read.

#define N_PTS 1024
#define HID   128
#define K_TAB 127                 // 127*128*4 = 65024 B table (fits 64KB static LDS)
#define A_MAX 12.0f               // max a_index = pi * 180/(15*pi) = 12 exactly
#define T_OF_ANGLE 40.1070456591f // (K_TAB-1)/pi = 126/pi
#define NEG_LOG1E4_OVER_128 (-0.0719557841f)

// ---------------- Kernel A: build table T[K_TAB][HID] (fp32, in ws) ----------------
// T[t][k] = b[k] + sum_m sin(a_t*w_m)*W[k][2m] + cos(a_t*w_m)*W[k][2m+1]
__global__ __launch_bounds__(128) void build_table(
        const float* __restrict__ W,
        const float* __restrict__ b,
        float* __restrict__ T) {
    __shared__ float ss[64], sc[64];
    const int t = blockIdx.x;                      // 0..K_TAB-1
    const float a = (float)t * (A_MAX / (float)(K_TAB - 1));
    const int k = threadIdx.x;                     // 0..127
    if (k < 64) {
        float omega = expf((float)(2 * k) * NEG_LOG1E4_OVER_128); // 10000^(-k/64)
        ss[k] = sinf(a * omega);
        sc[k] = cosf(a * omega);
    }
    __syncthreads();
    float acc = b[k];
    const float* wrow = W + k * HID;
#pragma unroll 8
    for (int m = 0; m < 64; ++m) {
        acc += ss[m] * wrow[2 * m] + sc[m] * wrow[2 * m + 1];
    }
    T[t * HID + k] = acc;
}

// ---------------- Kernel B (fused): angle -> lerp table -> stream out ----------------
// Each wave owns 64 consecutive pairs per outer iter:
//   phase 1: lane l computes t for pair base+l (i wave-uniform, j coalesced).
//   phase 2: 32 sub-iters; half-wave h handles row base+2k+h. t broadcast via
//            one ds_bpermute (__shfl with per-lane src index). 32 lanes x 16B
//            = 512B contiguous per row; wave stores 1KB per sub-iter.
__global__ __launch_bounds__(256) void fused_out(
        const float* __restrict__ normals,
        const float* __restrict__ T,
        float* __restrict__ out) {
    __shared__ float lt[K_TAB * HID];   // 65024 B -> 2 blocks/CU
    for (int idx = threadIdx.x; idx < (K_TAB * HID) / 4; idx += 256)
        ((float4*)lt)[idx] = ((const float4*)T)[idx];
    __syncthreads();

    const int lane = threadIdx.x & 63;
    const int half = lane >> 5;          // which of the 2 rows this half-wave writes
    const int l32  = lane & 31;
    const int gwave = (blockIdx.x * 256 + threadIdx.x) >> 6;
    const int nwave = (gridDim.x * 256) >> 6;     // 2048 waves @ grid=512

    for (int base = gwave * 64; base < N_PTS * N_PTS; base += nwave * 64) {
        // ---- phase 1: one pair per lane, angle -> table coordinate ----
        const int p = base + lane;
        const int i = p >> 10;           // wave-uniform (base % 64 == 0)
        const int j = p & 1023;          // consecutive across lanes
        float ax = normals[3 * i],  ay = normals[3 * i + 1], az = normals[3 * i + 2];
        float bx = normals[3 * j],  by = normals[3 * j + 1], bz = normals[3 * j + 2];
        float cx = ay * bz - az * by;
        float cy = az * bx - ax * bz;
        float cz = ax * by - ay * bx;
        float sv = sqrtf(cx * cx + cy * cy + cz * cz);
        float cv = ax * bx + ay * by + az * bz;
        float tval = atan2f(sv, cv) * T_OF_ANGLE;   // [0, 126]

        // ---- phase 2: lerp + stream; no global loads in this loop ----
        float* orow = out + (size_t)(base + half) * HID + l32 * 4;
#pragma unroll 4
        for (int k = 0; k < 32; ++k) {
            float t = __shfl(tval, 2 * k + half, 64);   // one ds_bpermute
            int idx = (int)t;                            // t >= 0 always
            idx = idx > K_TAB - 2 ? K_TAB - 2 : idx;
            float frac = t - (float)idx;
            const float4 v0 = *(const float4*)(lt + idx * HID + l32 * 4);
            const float4 v1 = *(const float4*)(lt + idx * HID + HID + l32 * 4);
            float4 r;
            r.x = fmaf(frac, v1.x - v0.x, v0.x);
            r.y = fmaf(frac, v1.y - v0.y, v0.y);
            r.z = fmaf(frac, v1.z - v0.z, v0.z);
            r.w = fmaf(frac, v1.w - v0.w, v0.w);
            *(float4*)orow = r;
            orow += 2 * HID;             // next sub-iter: rows base+2(k+1)+half
        }
    }
}

extern "C" void kernel_launch(void* const* d_in, const int* in_sizes, int n_in,
                              void* d_out, int out_size, void* d_ws, size_t ws_size,
                              hipStream_t stream) {
    // setup_inputs order: points (unused), normals, W, b — fp32 per reference
    const float* normals = (const float*)d_in[1];
    const float* W       = (const float*)d_in[2];
    const float* b       = (const float*)d_in[3];
    float* out           = (float*)d_out;

    float* T = (float*)d_ws;    // 65024 B table

    build_table<<<K_TAB, 128, 0, stream>>>(W, b, T);
    // 512 blocks = 2/CU (LDS-bound) -> exactly one residency round, 2048 waves,
    // 8 outer iters/wave, 64 rows (32 KB) streamed per wave-iter.
    fused_out<<<512, 256, 0, stream>>>(normals, T, out);
}

// Round 2
// 521.579 us; speedup vs baseline: 1.0939x; 1.0034x over previous
//
#include <hip/hip_runtime.h>
#include <hip/hip_fp16.h>
#include <math.h>

// out[i,j,:] = sinusoidal_emb(atan2(|n_i x n_j|, n_i.n_j) * 180/(15pi)) @ W.T + b
// N=1024^2 pairs, HIDDEN=128, fp32 out (512 MiB -> HBM-write floor ~87us).
// Output row is a smooth 1-D function of angle -> 127-row table of (emb@W.T+b),
// lerp per pair (lerp err ~7e-4; fp16 table adds ~2-4e-3; threshold 4.8e-2).
//
// R2: latency-targeted rewrite of the streaming kernel.
//  - fp16 LDS table (31.75 KB) -> 4 blocks/CU (was 2 @ fp32 63.5 KB).
//  - per-row (rowbyte, frac_h2) precomputed per lane in a prologue for ALL
//    outer iters; broadcast via v_readlane+cndmask (VALU) instead of
//    ds_bpermute -> sub-iter chain is one ds_read_b64, not two chained LDS ops.
//  - ZERO global loads in the streaming loop -> no vmcnt wait ever drains the
//    store queue; kernel is structurally a fill with an LDS/VALU preamble.

#define N_PTS 1024
#define HID   128
#define K_TAB 127                 // 127*128 halves = 32512 B LDS
#define A_MAX 12.0f               // max a_index = pi * 180/(15*pi) = 12 exactly
#define T_OF_ANGLE 40.1070456591f // (K_TAB-1)/pi = 126/pi
#define NEG_LOG1E4_OVER_128 (-0.0719557841f)
#define GRID_B 1024
#define OUTER  4                  // 1024 blk * 4 waves * 64 lanes * 4 = 1M pairs

// ---------------- Kernel A: build table T[K_TAB][HID] (fp32, in ws) ----------------
__global__ __launch_bounds__(128) void build_table(
        const float* __restrict__ W,
        const float* __restrict__ b,
        float* __restrict__ T) {
    __shared__ float ss[64], sc[64];
    const int t = blockIdx.x;                      // 0..K_TAB-1
    const float a = (float)t * (A_MAX / (float)(K_TAB - 1));
    const int k = threadIdx.x;                     // 0..127
    if (k < 64) {
        float omega = expf((float)(2 * k) * NEG_LOG1E4_OVER_128); // 10000^(-k/64)
        ss[k] = sinf(a * omega);
        sc[k] = cosf(a * omega);
    }
    __syncthreads();
    float acc = b[k];
    const float* wrow = W + k * HID;
#pragma unroll 8
    for (int m = 0; m < 64; ++m) {
        acc += ss[m] * wrow[2 * m] + sc[m] * wrow[2 * m + 1];
    }
    T[t * HID + k] = acc;
}

// ---------------- Kernel B: prologue (angles) + pure streaming loop ----------------
__global__ __launch_bounds__(256, 4) void fused_out(
        const float* __restrict__ normals,
        const float* __restrict__ T,
        float* __restrict__ out) {
    __shared__ __half lt[K_TAB * HID];   // 32512 B -> 4 blocks/CU at grid 1024
    for (int c = threadIdx.x; c < (K_TAB * HID) / 4; c += 256) {
        float4 v = ((const float4*)T)[c];
        ((__half2*)lt)[2 * c]     = __floats2half2_rn(v.x, v.y);
        ((__half2*)lt)[2 * c + 1] = __floats2half2_rn(v.z, v.w);
    }
    __syncthreads();

    const int lane  = threadIdx.x & 63;
    const int hsel  = lane >> 5;         // which of the 2 rows this half-wave writes
    const int l32   = lane & 31;
    const int gwave = (blockIdx.x * 256 + threadIdx.x) >> 6;
    const int STRIDE = GRID_B * 4 * 64;  // pairs per sweep (262144)

    // ---- prologue: all OUTER iters' angles -> (row byte offset, packed frac) ----
    int rowb_[OUTER];                    // idx * 256 (fp16 row stride in bytes)
    int frb_[OUTER];                     // frac as __half2 bits
#pragma unroll
    for (int o = 0; o < OUTER; ++o) {
        const int p = gwave * 64 + o * STRIDE + lane;
        const int i = p >> 10;           // wave-uniform
        const int j = p & 1023;          // consecutive across lanes
        float ax = normals[3 * i], ay = normals[3 * i + 1], az = normals[3 * i + 2];
        float bx = normals[3 * j], by = normals[3 * j + 1], bz = normals[3 * j + 2];
        float cx = ay * bz - az * by;
        float cy = az * bx - ax * bz;
        float cz = ax * by - ay * bx;
        float sv = sqrtf(cx * cx + cy * cy + cz * cz);
        float cv = ax * bx + ay * by + az * bz;
        float t  = atan2f(sv, cv) * T_OF_ANGLE;    // [0, 126]
        int idx = (int)t;
        idx = idx > K_TAB - 2 ? K_TAB - 2 : idx;   // t=126.0 -> idx=125, frac=1.0
        float frac = t - (float)idx;
        rowb_[o] = idx * (HID * 2);
        __half2 f2 = __float2half2_rn(frac);
        frb_[o] = __builtin_bit_cast(int, f2);
    }

    // ---- streaming loop: LDS + VALU + stores only (no global loads) ----
    const char* ltb = (const char*)lt;
    const int laneoff = l32 * 8;         // 4 halves per lane per row
#pragma unroll
    for (int o = 0; o < OUTER; ++o) {
        float* orow = out + (size_t)(gwave * 64 + o * STRIDE + hsel) * HID + l32 * 4;
#pragma unroll
        for (int k = 0; k < 32; ++k) {
            int rb0 = __builtin_amdgcn_readlane(rowb_[o], 2 * k);
            int rb1 = __builtin_amdgcn_readlane(rowb_[o], 2 * k + 1);
            int fb0 = __builtin_amdgcn_readlane(frb_[o], 2 * k);
            int fb1 = __builtin_amdgcn_readlane(frb_[o], 2 * k + 1);
            int rb = hsel ? rb1 : rb0;
            int fb = hsel ? fb1 : fb0;
            const char* pa = ltb + rb + laneoff;
            uint2 ua = *(const uint2*)(pa);              // row idx   (4 halves)
            uint2 ub = *(const uint2*)(pa + HID * 2);    // row idx+1 (4 halves)
            __half2 a0 = __builtin_bit_cast(__half2, ua.x);
            __half2 a1 = __builtin_bit_cast(__half2, ua.y);
            __half2 b0 = __builtin_bit_cast(__half2, ub.x);
            __half2 b1 = __builtin_bit_cast(__half2, ub.y);
            __half2 fr2 = __builtin_bit_cast(__half2, fb);
            __half2 r0 = __hfma2(fr2, __hsub2(b0, a0), a0);
            __half2 r1 = __hfma2(fr2, __hsub2(b1, a1), a1);
            float2 f0 = __half22float2(r0);
            float2 f1 = __half22float2(r1);
            float4 rv = make_float4(f0.x, f0.y, f1.x, f1.y);
            *(float4*)orow = rv;         // 64 lanes x 16B = 1KB contiguous/instr
            orow += 2 * HID;
        }
    }
}

extern "C" void kernel_launch(void* const* d_in, const int* in_sizes, int n_in,
                              void* d_out, int out_size, void* d_ws, size_t ws_size,
                              hipStream_t stream) {
    // setup_inputs order: points (unused), normals, W, b — fp32 per reference
    const float* normals = (const float*)d_in[1];
    const float* W       = (const float*)d_in[2];
    const float* b       = (const float*)d_in[3];
    float* out           = (float*)d_out;

    float* T = (float*)d_ws;    // 65024 B fp32 table

    build_table<<<K_TAB, 128, 0, stream>>>(W, b, T);
    // 1024 blocks = 4/CU (31.75 KB LDS each), 4096 waves, 4 outer iters/wave.
    fused_out<<<GRID_B, 256, 0, stream>>>(normals, T, out);
}